// Round 6
// baseline (224.948 us; speedup 1.0000x reference)
//
#include <hip/hip_runtime.h>

#define BB   256
#define NIMG 49
#define NGPS 32
#define DIM  256
#define MPAD 64

typedef __attribute__((ext_vector_type(8))) __bf16 bf16x8;
typedef __attribute__((ext_vector_type(4))) float  f32x4;
typedef __attribute__((ext_vector_type(4))) unsigned short u16x4;

__device__ inline unsigned short f2bf(float f) {
  unsigned int u = __float_as_uint(f);
  u += 0x7fff + ((u >> 16) & 1);   // round-to-nearest-even
  return (unsigned short)(u >> 16);
}

// DPP cross-lane reduce helpers (VALU pipe, no DS traffic).
template<int CTRL>
__device__ inline float dppmax(float v) {
  float o = __int_as_float(__builtin_amdgcn_update_dpp(0, __float_as_int(v), CTRL, 0xF, 0xF, true));
  return fmaxf(v, o);
}
template<int CTRL>
__device__ inline float dppadd(float v) {
  float o = __int_as_float(__builtin_amdgcn_update_dpp(0, __float_as_int(v), CTRL, 0xF, 0xF, true));
  return v + o;
}
__device__ inline float max16(float v) {   // max across the 16 lanes of a DPP row
  v = dppmax<0xB1>(v); v = dppmax<0x4E>(v); v = dppmax<0x141>(v); v = dppmax<0x140>(v);
  return v;
}
__device__ inline float sum16(float v) {   // sum across the 16 lanes of a DPP row
  v = dppadd<0xB1>(v); v = dppadd<0x4E>(v); v = dppadd<0x141>(v); v = dppadd<0x140>(v);
  return v;
}

// ---------------- kernel 1: L2-normalize + cast to bf16 (img padded to 64 rows/b) ----
__global__ __launch_bounds__(256) void norm_kernel(
    const float* __restrict__ img, const float* __restrict__ gps,
    unsigned short* __restrict__ imgN, unsigned short* __restrict__ gpsN)
{
  int w    = (blockIdx.x * 256 + threadIdx.x) >> 6;  // one wave per row
  int lane = threadIdx.x & 63;
  const float* src;
  unsigned short* dst;
  if (w < BB * MPAD) {
    int b = w >> 6, n = w & 63;
    dst = imgN + (size_t)w * DIM;
    if (n >= NIMG) {                                  // zero padding rows
      u16x4 z = {0, 0, 0, 0};
      *reinterpret_cast<u16x4*>(dst + lane * 4) = z;
      return;
    }
    src = img + ((size_t)b * NIMG + n) * DIM;
  } else {
    int t = w - BB * MPAD;
    dst = gpsN + (size_t)t * DIM;
    src = gps + (size_t)t * DIM;
  }
  f32x4 x = *reinterpret_cast<const f32x4*>(src + lane * 4);
  float ss = x[0]*x[0] + x[1]*x[1] + x[2]*x[2] + x[3]*x[3];
  #pragma unroll
  for (int d = 1; d < 64; d <<= 1) ss += __shfl_xor(ss, d);
  float inv = 1.0f / fmaxf(sqrtf(ss), 1e-12f);
  u16x4 o;
  o[0] = f2bf(x[0]*inv); o[1] = f2bf(x[1]*inv);
  o[2] = f2bf(x[2]*inv); o[3] = f2bf(x[3]*inv);
  *reinterpret_cast<u16x4*>(dst + lane * 4) = o;
}

// ---------------- kernel 2: all-pairs MFMA + fused max/mean reductions --------------
// grid: 2048 blocks = 256 b * 8 g-chunks; 4 waves/block, each wave owns 8 g's,
// processed ONE at a time (minimum register state -> 4 waves/SIMD occupancy).
// A (img[b], 64x256 bf16 = 32KB) staged once in LDS, XOR-swizzled.
// TRANSPOSED mfma: gps frag = A-operand, img frag = B-operand -> D = S^T
//   (rows = gps m = mt*16+grp*4+r, cols = img n = hf*16+c).
// Register budget is THE lever (512 regs/SIMD pool: <=128 -> 4 waves, <=170 -> 3,
// <=256 -> 2). Hand count ~100 combined. (256,3) caps at 170: zero spill risk,
// allocator still free to land <=128 for 4 waves. r3 lesson: never force past need.
__global__ __launch_bounds__(256, 3) void pair_kernel(
    const unsigned short* __restrict__ imgN, const unsigned short* __restrict__ gpsN,
    float* __restrict__ i2g, float* __restrict__ g2i)
{
  int tid  = threadIdx.x;
  int wv   = tid >> 6;
  int lane = tid & 63;
  int c    = lane & 15, grp = lane >> 4;
  int b    = blockIdx.x >> 3, gc = blockIdx.x & 7;

  __shared__ unsigned short As[MPAD * DIM];   // 32 KB

  // ---- stage A: lane = row, each wave writes 8 of 32 16B-slots per row ----
  {
    const unsigned short* src = imgN + ((size_t)(b * MPAD + lane)) * DIM;
    unsigned int rb = lane * 512;             // row byte base (512 B/row)
    unsigned int sw = (lane & 7) << 4;        // XOR swizzle for this row
    #pragma unroll
    for (int i = 0; i < 8; ++i) {
      int s = wv * 8 + i;                     // 16B slot index 0..31
      bf16x8 v = *reinterpret_cast<const bf16x8*>(src + s * 8);
      *reinterpret_cast<bf16x8*>(reinterpret_cast<char*>(As) + ((rb + s * 16) ^ sw)) = v;
    }
  }
  __syncthreads();

  const char* Ab = reinterpret_cast<const char*>(As);
  unsigned int swr   = (c & 7) << 4;          // read-side swizzle
  unsigned int abase = c * 512;               // + hf*8192 + ((grp*16 + kc*64)^swr)

  int gfirst = gc * 32 + wv * 8;
  // single gps base pointer; mt=1 is +4096 elements, kc is +32 elements, g is +8192
  const unsigned short* pg = gpsN + ((size_t)gfirst * NGPS + c) * DIM + grp * 8;

  #pragma unroll 1
  for (int gi = 0; gi < 8; ++gi) {
    f32x4 acc[2][4];                           // [mt (gps rows)][hf (img cols)]
    #pragma unroll
    for (int mt = 0; mt < 2; ++mt)
      #pragma unroll
      for (int hf = 0; hf < 4; ++hf)
        acc[mt][hf] = (f32x4){0.f, 0.f, 0.f, 0.f};

    #pragma unroll
    for (int kc = 0; kc < 8; ++kc) {
      bf16x8 q0 = *reinterpret_cast<const bf16x8*>(pg + kc * 32);          // mt=0
      bf16x8 q1 = *reinterpret_cast<const bf16x8*>(pg + 4096 + kc * 32);   // mt=1
      unsigned int off = ((unsigned)(grp * 16 + kc * 64)) ^ swr;
      const char* ab = Ab + abase + off;
      bf16x8 a0 = *reinterpret_cast<const bf16x8*>(ab);
      bf16x8 a1 = *reinterpret_cast<const bf16x8*>(ab + 8192);
      bf16x8 a2 = *reinterpret_cast<const bf16x8*>(ab + 16384);
      bf16x8 a3 = *reinterpret_cast<const bf16x8*>(ab + 24576);
      acc[0][0] = __builtin_amdgcn_mfma_f32_16x16x32_bf16(q0, a0, acc[0][0], 0, 0, 0);
      acc[0][1] = __builtin_amdgcn_mfma_f32_16x16x32_bf16(q0, a1, acc[0][1], 0, 0, 0);
      acc[0][2] = __builtin_amdgcn_mfma_f32_16x16x32_bf16(q0, a2, acc[0][2], 0, 0, 0);
      acc[0][3] = __builtin_amdgcn_mfma_f32_16x16x32_bf16(q0, a3, acc[0][3], 0, 0, 0);
      acc[1][0] = __builtin_amdgcn_mfma_f32_16x16x32_bf16(q1, a0, acc[1][0], 0, 0, 0);
      acc[1][1] = __builtin_amdgcn_mfma_f32_16x16x32_bf16(q1, a1, acc[1][1], 0, 0, 0);
      acc[1][2] = __builtin_amdgcn_mfma_f32_16x16x32_bf16(q1, a2, acc[1][2], 0, 0, 0);
      acc[1][3] = __builtin_amdgcn_mfma_f32_16x16x32_bf16(q1, a3, acc[1][3], 0, 0, 0);
    }

    // ---- epilogue: D = S^T, row m = mt*16+grp*4+r (gps), col n = hf*16+c (img) ----
    // i2g: mean over n<49 of (max over m). max over m: in-lane (mt,r) + xor16/32.
    float vmax[4];
    #pragma unroll
    for (int hf = 0; hf < 4; ++hf) {
      float m0 = fmaxf(fmaxf(acc[0][hf][0], acc[0][hf][1]),
                       fmaxf(acc[0][hf][2], acc[0][hf][3]));
      float m1 = fmaxf(fmaxf(acc[1][hf][0], acc[1][hf][1]),
                       fmaxf(acc[1][hf][2], acc[1][hf][3]));
      float vm = fmaxf(m0, m1);
      vm = fmaxf(vm, __shfl_xor(vm, 16));
      vm = fmaxf(vm, __shfl_xor(vm, 32));
      vmax[hf] = vm;
    }
    // valid n: hf<3 all 16 c's; hf==3 only c==0 (n=48)
    float s = vmax[0] + vmax[1] + vmax[2] + ((c == 0) ? vmax[3] : 0.0f);
    s = sum16(s);                              // sum over c -> sum over n<49

    // g2i: mean over 32 m of (max over n<49). in-lane over hf (mask hf3), max16
    // over c, then sum over (mt,r) in-lane + xor16/32 over grp.
    float t = 0.f;
    #pragma unroll
    for (int mt = 0; mt < 2; ++mt)
      #pragma unroll
      for (int r = 0; r < 4; ++r) {
        float h3 = (c == 0) ? acc[mt][3][r] : -1.0e30f;
        float hm = fmaxf(fmaxf(acc[mt][0][r], acc[mt][1][r]),
                         fmaxf(acc[mt][2][r], h3));
        hm = max16(hm);
        t += hm;
      }
    t += __shfl_xor(t, 16);
    t += __shfl_xor(t, 32);

    if (lane == 0) {
      int g = gfirst + gi;
      i2g[b * 256 + g] = s * (1.0f / NIMG);
      g2i[g * 256 + b] = t * (1.0f / NGPS);
    }
    pg += NGPS * DIM;                          // next g
  }
}

// ---------------- kernel 3: per-row CE partials -------------------------------------
__global__ __launch_bounds__(256) void ce_kernel(
    const float* __restrict__ i2g, const float* __restrict__ g2i,
    const float* __restrict__ lsp, float* __restrict__ partial)
{
  int b = blockIdx.x, t = threadIdx.x, lane = t & 63, wv = t >> 6;
  float s = fminf(expf(lsp[0]), 100.0f);
  float v1 = s * i2g[b * 256 + t];
  float v2 = s * g2i[b * 256 + t];

  float m1 = v1, m2 = v2;
  #pragma unroll
  for (int d = 1; d < 64; d <<= 1) {
    m1 = fmaxf(m1, __shfl_xor(m1, d));
    m2 = fmaxf(m2, __shfl_xor(m2, d));
  }
  __shared__ float sm[2][4];
  if (lane == 0) { sm[0][wv] = m1; sm[1][wv] = m2; }
  __syncthreads();
  m1 = fmaxf(fmaxf(sm[0][0], sm[0][1]), fmaxf(sm[0][2], sm[0][3]));
  m2 = fmaxf(fmaxf(sm[1][0], sm[1][1]), fmaxf(sm[1][2], sm[1][3]));

  float e1 = expf(v1 - m1), e2 = expf(v2 - m2);
  #pragma unroll
  for (int d = 1; d < 64; d <<= 1) {
    e1 += __shfl_xor(e1, d);
    e2 += __shfl_xor(e2, d);
  }
  __shared__ float se[2][4];
  if (lane == 0) { se[0][wv] = e1; se[1][wv] = e2; }
  __syncthreads();
  if (t == 0) {
    float S1 = se[0][0] + se[0][1] + se[0][2] + se[0][3];
    float S2 = se[1][0] + se[1][1] + se[1][2] + se[1][3];
    float lse1 = m1 + logf(S1);
    float lse2 = m2 + logf(S2);
    partial[b] = (lse1 - s * i2g[b * 257]) + (lse2 - s * g2i[b * 257]);
  }
}

// ---------------- kernel 4: final scalar --------------------------------------------
__global__ __launch_bounds__(256) void finish_kernel(
    const float* __restrict__ partial, float* __restrict__ out)
{
  int t = threadIdx.x, lane = t & 63, wv = t >> 6;
  float v = partial[t];
  #pragma unroll
  for (int d = 1; d < 64; d <<= 1) v += __shfl_xor(v, d);
  __shared__ float sp[4];
  if (lane == 0) sp[wv] = v;
  __syncthreads();
  if (t == 0) out[0] = (sp[0] + sp[1] + sp[2] + sp[3]) * (1.0f / 512.0f);
}

extern "C" void kernel_launch(void* const* d_in, const int* in_sizes, int n_in,
                              void* d_out, int out_size, void* d_ws, size_t ws_size,
                              hipStream_t stream)
{
  const float* img = (const float*)d_in[0];
  const float* gps = (const float*)d_in[1];
  const float* lsp = (const float*)d_in[2];
  float* out = (float*)d_out;
  char* ws = (char*)d_ws;

  unsigned short* imgN = (unsigned short*)(ws);              //  8,388,608 B
  unsigned short* gpsN = (unsigned short*)(ws + 8388608);    //  4,194,304 B
  float* i2g     = (float*)(ws + 12582912);                  //    262,144 B
  float* g2i     = (float*)(ws + 12845056);                  //    262,144 B
  float* partial = (float*)(ws + 13107200);                  //      1,024 B

  norm_kernel<<<6144, 256, 0, stream>>>(img, gps, imgN, gpsN);
  pair_kernel<<<2048, 256, 0, stream>>>(imgN, gpsN, i2g, g2i);
  ce_kernel<<<256, 256, 0, stream>>>(i2g, g2i, lsp, partial);
  finish_kernel<<<1, 256, 0, stream>>>(partial, out);
}

// Round 7
// 143.013 us; speedup vs baseline: 1.5729x; 1.5729x over previous
//
#include <hip/hip_runtime.h>

#define BB   256
#define NIMG 49
#define NGPS 32
#define DIM  256
#define MPAD 64

typedef __attribute__((ext_vector_type(8))) __bf16 bf16x8;
typedef __attribute__((ext_vector_type(4))) float  f32x4;
typedef __attribute__((ext_vector_type(4))) unsigned short u16x4;

__device__ inline unsigned short f2bf(float f) {
  unsigned int u = __float_as_uint(f);
  u += 0x7fff + ((u >> 16) & 1);   // round-to-nearest-even
  return (unsigned short)(u >> 16);
}

// DPP cross-lane reduce helpers (VALU pipe, no DS traffic).
template<int CTRL>
__device__ inline float dppmax(float v) {
  float o = __int_as_float(__builtin_amdgcn_update_dpp(0, __float_as_int(v), CTRL, 0xF, 0xF, true));
  return fmaxf(v, o);
}
template<int CTRL>
__device__ inline float dppadd(float v) {
  float o = __int_as_float(__builtin_amdgcn_update_dpp(0, __float_as_int(v), CTRL, 0xF, 0xF, true));
  return v + o;
}
__device__ inline float max16(float v) {   // max across the 16 lanes of a DPP row
  v = dppmax<0xB1>(v); v = dppmax<0x4E>(v); v = dppmax<0x141>(v); v = dppmax<0x140>(v);
  return v;
}
__device__ inline float sum16(float v) {   // sum across the 16 lanes of a DPP row
  v = dppadd<0xB1>(v); v = dppadd<0x4E>(v); v = dppadd<0x141>(v); v = dppadd<0x140>(v);
  return v;
}

// ---------------- kernel 1: L2-normalize + cast to bf16 (img padded to 64 rows/b) ----
__global__ __launch_bounds__(256) void norm_kernel(
    const float* __restrict__ img, const float* __restrict__ gps,
    unsigned short* __restrict__ imgN, unsigned short* __restrict__ gpsN)
{
  int w    = (blockIdx.x * 256 + threadIdx.x) >> 6;  // one wave per row
  int lane = threadIdx.x & 63;
  const float* src;
  unsigned short* dst;
  if (w < BB * MPAD) {
    int b = w >> 6, n = w & 63;
    dst = imgN + (size_t)w * DIM;
    if (n >= NIMG) {                                  // zero padding rows
      u16x4 z = {0, 0, 0, 0};
      *reinterpret_cast<u16x4*>(dst + lane * 4) = z;
      return;
    }
    src = img + ((size_t)b * NIMG + n) * DIM;
  } else {
    int t = w - BB * MPAD;
    dst = gpsN + (size_t)t * DIM;
    src = gps + (size_t)t * DIM;
  }
  f32x4 x = *reinterpret_cast<const f32x4*>(src + lane * 4);
  float ss = x[0]*x[0] + x[1]*x[1] + x[2]*x[2] + x[3]*x[3];
  #pragma unroll
  for (int d = 1; d < 64; d <<= 1) ss += __shfl_xor(ss, d);
  float inv = 1.0f / fmaxf(sqrtf(ss), 1e-12f);
  u16x4 o;
  o[0] = f2bf(x[0]*inv); o[1] = f2bf(x[1]*inv);
  o[2] = f2bf(x[2]*inv); o[3] = f2bf(x[3]*inv);
  *reinterpret_cast<u16x4*>(dst + lane * 4) = o;
}

// ---------------- kernel 2: all-pairs MFMA + fused max/mean reductions --------------
// grid: 2048 blocks = 256 b * 8 g-chunks; 4 waves/block, each wave owns 8 g's,
// processed ONE at a time (acc = 32 AGPR only).
// A (img[b], 64x256 bf16 = 32KB) staged once in LDS, XOR-swizzled.
// TRANSPOSED mfma: gps frag = A-operand, img frag = B-operand -> D = S^T.
// REGISTER-PRESSURE CONTROL (r3/r5/r6 lessons): the kc loop is `#pragma unroll 2`.
// Full unroll let the scheduler hoist all 8 iterations' loads (~190 live regs):
// uncapped -> 1 wave/SIMD (r5); capped (256,3) -> 75-148MB spill (r3,r6).
// Unroll-2 bounds in-flight loads to ~48 regs -> fits the 170 cap, no spill.
__global__ __launch_bounds__(256, 3) void pair_kernel(
    const unsigned short* __restrict__ imgN, const unsigned short* __restrict__ gpsN,
    float* __restrict__ i2g, float* __restrict__ g2i)
{
  int tid  = threadIdx.x;
  int wv   = tid >> 6;
  int lane = tid & 63;
  int c    = lane & 15, grp = lane >> 4;
  int b    = blockIdx.x >> 3, gc = blockIdx.x & 7;

  __shared__ unsigned short As[MPAD * DIM];   // 32 KB

  // ---- stage A: lane = row, each wave writes 8 of 32 16B-slots per row ----
  {
    const unsigned short* src = imgN + ((size_t)(b * MPAD + lane)) * DIM;
    unsigned int rb = lane * 512;             // row byte base (512 B/row)
    unsigned int sw = (lane & 7) << 4;        // XOR swizzle for this row
    #pragma unroll
    for (int i = 0; i < 8; ++i) {
      int s = wv * 8 + i;                     // 16B slot index 0..31
      bf16x8 v = *reinterpret_cast<const bf16x8*>(src + s * 8);
      *reinterpret_cast<bf16x8*>(reinterpret_cast<char*>(As) + ((rb + s * 16) ^ sw)) = v;
    }
  }
  __syncthreads();

  const char* Ab = reinterpret_cast<const char*>(As);
  unsigned int swr   = (c & 7) << 4;          // read-side swizzle
  unsigned int abase = c * 512;               // + hf*8192 + ((grp*16 + kc*64)^swr)

  int gfirst = gc * 32 + wv * 8;
  // single gps base pointer; mt=1 is +4096 elements, kc is +32 elements, g is +8192
  const unsigned short* pg = gpsN + ((size_t)gfirst * NGPS + c) * DIM + grp * 8;

  #pragma unroll 1
  for (int gi = 0; gi < 8; ++gi) {
    f32x4 acc[2][4];                           // [mt (gps rows)][hf (img cols)]
    #pragma unroll
    for (int mt = 0; mt < 2; ++mt)
      #pragma unroll
      for (int hf = 0; hf < 4; ++hf)
        acc[mt][hf] = (f32x4){0.f, 0.f, 0.f, 0.f};

    #pragma unroll 2
    for (int kc = 0; kc < 8; ++kc) {
      bf16x8 q0 = *reinterpret_cast<const bf16x8*>(pg + kc * 32);          // mt=0
      bf16x8 q1 = *reinterpret_cast<const bf16x8*>(pg + 4096 + kc * 32);   // mt=1
      unsigned int off = ((unsigned)(grp * 16 + kc * 64)) ^ swr;
      const char* ab = Ab + abase + off;
      bf16x8 a0 = *reinterpret_cast<const bf16x8*>(ab);
      bf16x8 a1 = *reinterpret_cast<const bf16x8*>(ab + 8192);
      bf16x8 a2 = *reinterpret_cast<const bf16x8*>(ab + 16384);
      bf16x8 a3 = *reinterpret_cast<const bf16x8*>(ab + 24576);
      acc[0][0] = __builtin_amdgcn_mfma_f32_16x16x32_bf16(q0, a0, acc[0][0], 0, 0, 0);
      acc[0][1] = __builtin_amdgcn_mfma_f32_16x16x32_bf16(q0, a1, acc[0][1], 0, 0, 0);
      acc[0][2] = __builtin_amdgcn_mfma_f32_16x16x32_bf16(q0, a2, acc[0][2], 0, 0, 0);
      acc[0][3] = __builtin_amdgcn_mfma_f32_16x16x32_bf16(q0, a3, acc[0][3], 0, 0, 0);
      acc[1][0] = __builtin_amdgcn_mfma_f32_16x16x32_bf16(q1, a0, acc[1][0], 0, 0, 0);
      acc[1][1] = __builtin_amdgcn_mfma_f32_16x16x32_bf16(q1, a1, acc[1][1], 0, 0, 0);
      acc[1][2] = __builtin_amdgcn_mfma_f32_16x16x32_bf16(q1, a2, acc[1][2], 0, 0, 0);
      acc[1][3] = __builtin_amdgcn_mfma_f32_16x16x32_bf16(q1, a3, acc[1][3], 0, 0, 0);
    }

    // ---- epilogue: D = S^T, row m = mt*16+grp*4+r (gps), col n = hf*16+c (img) ----
    // i2g: mean over n<49 of (max over m). max over m: in-lane (mt,r) + xor16/32.
    float vmax[4];
    #pragma unroll
    for (int hf = 0; hf < 4; ++hf) {
      float m0 = fmaxf(fmaxf(acc[0][hf][0], acc[0][hf][1]),
                       fmaxf(acc[0][hf][2], acc[0][hf][3]));
      float m1 = fmaxf(fmaxf(acc[1][hf][0], acc[1][hf][1]),
                       fmaxf(acc[1][hf][2], acc[1][hf][3]));
      float vm = fmaxf(m0, m1);
      vm = fmaxf(vm, __shfl_xor(vm, 16));
      vm = fmaxf(vm, __shfl_xor(vm, 32));
      vmax[hf] = vm;
    }
    // valid n: hf<3 all 16 c's; hf==3 only c==0 (n=48)
    float s = vmax[0] + vmax[1] + vmax[2] + ((c == 0) ? vmax[3] : 0.0f);
    s = sum16(s);                              // sum over c -> sum over n<49

    // g2i: mean over 32 m of (max over n<49). in-lane over hf (mask hf3), max16
    // over c, then sum over (mt,r) in-lane + xor16/32 over grp.
    float t = 0.f;
    #pragma unroll
    for (int mt = 0; mt < 2; ++mt)
      #pragma unroll
      for (int r = 0; r < 4; ++r) {
        float h3 = (c == 0) ? acc[mt][3][r] : -1.0e30f;
        float hm = fmaxf(fmaxf(acc[mt][0][r], acc[mt][1][r]),
                         fmaxf(acc[mt][2][r], h3));
        hm = max16(hm);
        t += hm;
      }
    t += __shfl_xor(t, 16);
    t += __shfl_xor(t, 32);

    if (lane == 0) {
      int g = gfirst + gi;
      i2g[b * 256 + g] = s * (1.0f / NIMG);
      g2i[g * 256 + b] = t * (1.0f / NGPS);
    }
    pg += NGPS * DIM;                          // next g
  }
}

// ---------------- kernel 3: per-row CE partials -------------------------------------
__global__ __launch_bounds__(256) void ce_kernel(
    const float* __restrict__ i2g, const float* __restrict__ g2i,
    const float* __restrict__ lsp, float* __restrict__ partial)
{
  int b = blockIdx.x, t = threadIdx.x, lane = t & 63, wv = t >> 6;
  float s = fminf(expf(lsp[0]), 100.0f);
  float v1 = s * i2g[b * 256 + t];
  float v2 = s * g2i[b * 256 + t];

  float m1 = v1, m2 = v2;
  #pragma unroll
  for (int d = 1; d < 64; d <<= 1) {
    m1 = fmaxf(m1, __shfl_xor(m1, d));
    m2 = fmaxf(m2, __shfl_xor(m2, d));
  }
  __shared__ float sm[2][4];
  if (lane == 0) { sm[0][wv] = m1; sm[1][wv] = m2; }
  __syncthreads();
  m1 = fmaxf(fmaxf(sm[0][0], sm[0][1]), fmaxf(sm[0][2], sm[0][3]));
  m2 = fmaxf(fmaxf(sm[1][0], sm[1][1]), fmaxf(sm[1][2], sm[1][3]));

  float e1 = expf(v1 - m1), e2 = expf(v2 - m2);
  #pragma unroll
  for (int d = 1; d < 64; d <<= 1) {
    e1 += __shfl_xor(e1, d);
    e2 += __shfl_xor(e2, d);
  }
  __shared__ float se[2][4];
  if (lane == 0) { se[0][wv] = e1; se[1][wv] = e2; }
  __syncthreads();
  if (t == 0) {
    float S1 = se[0][0] + se[0][1] + se[0][2] + se[0][3];
    float S2 = se[1][0] + se[1][1] + se[1][2] + se[1][3];
    float lse1 = m1 + logf(S1);
    float lse2 = m2 + logf(S2);
    partial[b] = (lse1 - s * i2g[b * 257]) + (lse2 - s * g2i[b * 257]);
  }
}

// ---------------- kernel 4: final scalar --------------------------------------------
__global__ __launch_bounds__(256) void finish_kernel(
    const float* __restrict__ partial, float* __restrict__ out)
{
  int t = threadIdx.x, lane = t & 63, wv = t >> 6;
  float v = partial[t];
  #pragma unroll
  for (int d = 1; d < 64; d <<= 1) v += __shfl_xor(v, d);
  __shared__ float sp[4];
  if (lane == 0) sp[wv] = v;
  __syncthreads();
  if (t == 0) out[0] = (sp[0] + sp[1] + sp[2] + sp[3]) * (1.0f / 512.0f);
}

extern "C" void kernel_launch(void* const* d_in, const int* in_sizes, int n_in,
                              void* d_out, int out_size, void* d_ws, size_t ws_size,
                              hipStream_t stream)
{
  const float* img = (const float*)d_in[0];
  const float* gps = (const float*)d_in[1];
  const float* lsp = (const float*)d_in[2];
  float* out = (float*)d_out;
  char* ws = (char*)d_ws;

  unsigned short* imgN = (unsigned short*)(ws);              //  8,388,608 B
  unsigned short* gpsN = (unsigned short*)(ws + 8388608);    //  4,194,304 B
  float* i2g     = (float*)(ws + 12582912);                  //    262,144 B
  float* g2i     = (float*)(ws + 12845056);                  //    262,144 B
  float* partial = (float*)(ws + 13107200);                  //      1,024 B

  norm_kernel<<<6144, 256, 0, stream>>>(img, gps, imgN, gpsN);
  pair_kernel<<<2048, 256, 0, stream>>>(imgN, gpsN, i2g, g2i);
  ce_kernel<<<256, 256, 0, stream>>>(i2g, g2i, lsp, partial);
  finish_kernel<<<1, 256, 0, stream>>>(partial, out);
}